// Round 3
// baseline (332.717 us; speedup 1.0000x reference)
//
#include <hip/hip_runtime.h>

#define HD 64
#define ED 16
#define NB 16                 // nodes per fused block
#define OSTR 144              // bytes per o-row in LDS (9 x 16B slots: k 0..71)
#define NSTR 9232             // bytes per node in LDS (64*144 + 16 pad)
#define LDSB (NB*NSTR)        // 147712 bytes dynamic LDS

typedef __bf16 bf16x8 __attribute__((ext_vector_type(8)));
typedef float  f32x4  __attribute__((ext_vector_type(4)));
typedef unsigned int u32;
typedef unsigned long long u64;
typedef unsigned short u16;

static inline __device__ float bf2f(u16 u){
    union { u32 i; float f; } v; v.i = ((u32)u) << 16; return v.f;
}
static inline __device__ u16 f2bf(float f){
    union { u32 i; float f; } v; v.f = f;
    u32 r = v.i + 0x7FFF + ((v.i >> 16) & 1);
    return (u16)(r >> 16);
}
static inline __device__ u32 pk2(float a, float b){
    return (u32)f2bf(a) | ((u32)f2bf(b) << 16);
}

__global__ void k_zero2(int* a, int* b, int n){
    int i = blockIdx.x*blockDim.x + threadIdx.x;
    if(i < n){ a[i] = 0; b[i] = 0; }
}
__global__ void k_zerof(float* a, int n){
    int i = blockIdx.x*blockDim.x + threadIdx.x;
    if(i < n) a[i] = 0.f;
}
__global__ void k_deg(const int* __restrict__ src, const int* __restrict__ dst, int E,
                      int* __restrict__ degs, int* __restrict__ degd){
    int e = blockIdx.x*blockDim.x + threadIdx.x;
    if(e < E){ atomicAdd(&degs[src[e]], 1); atomicAdd(&degd[dst[e]], 1); }
}

// single-block scan: deg_src -> rowptr/cursor ; deg_dst -> countsf = max(deg,1)
__global__ void k_scan(const int* __restrict__ degs, const int* __restrict__ degd, int N,
                       int* __restrict__ rowptr, int* __restrict__ cursor, float* __restrict__ countsf){
    __shared__ int part[1024];
    int tid = threadIdx.x;
    int PER = (N + 1023) >> 10;
    int base = tid * PER;
    int local[16];
    int s = 0;
    for(int j = 0; j < PER; j++){
        int idx = base + j;
        int v = (idx < N) ? degs[idx] : 0;
        local[j] = s; s += v;
    }
    part[tid] = s;
    __syncthreads();
    for(int off = 1; off < 1024; off <<= 1){
        int v = (tid >= off) ? part[tid - off] : 0;
        __syncthreads();
        part[tid] += v;
        __syncthreads();
    }
    int prev = (tid == 0) ? 0 : part[tid - 1];
    for(int j = 0; j < PER; j++){
        int idx = base + j;
        if(idx < N){
            int r = prev + local[j];
            rowptr[idx] = r; cursor[idx] = r;
            int dd = degd[idx];
            countsf[idx] = (dd > 0) ? (float)dd : 1.0f;
        }
    }
    if(tid == 1023) rowptr[N] = prev + s;
}

__global__ void k_fill(const int* __restrict__ src, int E, int* __restrict__ cursor, int* __restrict__ elist){
    int e = blockIdx.x*blockDim.x + threadIdx.x;
    if(e < E){ int p = atomicAdd(&cursor[src[e]], 1); elist[p] = e; }
}

// h1E[p] = bf16(relu(edge_attr[elist[p]] @ W1 + b1)) in CSR order; dstE[p] = dst[elist[p]]
__global__ void k_h1E(const float* __restrict__ ea, const float* __restrict__ W1,
                      const float* __restrict__ b1, const int* __restrict__ elist,
                      const int* __restrict__ dstarr, int E,
                      u16* __restrict__ h1E, int* __restrict__ dstE){
    __shared__ float s_ea[4][ED];
    __shared__ int s_e[4];
    int t = threadIdx.x;              // 256
    int o = t & 63, el = t >> 6;
    int p = blockIdx.x*4 + el;
    if(t < 4){
        int pp = blockIdx.x*4 + t;
        s_e[t] = (pp < E) ? elist[pp] : 0;
    }
    __syncthreads();
    if(t < 4*ED){
        int pe = t/ED;
        s_ea[pe][t%ED] = ea[(size_t)s_e[pe]*ED + t%ED];
    }
    __syncthreads();
    if(p < E){
        float acc = b1[o];
        #pragma unroll
        for(int k = 0; k < ED; k++) acc += s_ea[el][k] * W1[k*HD + o];
        h1E[(size_t)p*HD + o] = f2bf(acc > 0.f ? acc : 0.f);
        if(o == 0) dstE[p] = dstarr[s_e[el]];
    }
}

// PT[c][i] = bf16( c=kc*64+o : kc<64 ? W2[kc][i*64+o] : b2[i*64+o] )   (4160 x 64)
__global__ void k_permT(const float* __restrict__ W2, const float* __restrict__ b2,
                        u16* __restrict__ PT){
    int idx = blockIdx.x*blockDim.x + threadIdx.x;
    if(idx >= 65*HD*HD) return;
    int c = idx / HD, i = idx % HD;
    int kc = c >> 6, o = c & 63;
    float v = (kc < HD) ? W2[(size_t)kc*(HD*HD) + i*HD + o] : b2[i*HD + o];
    PT[idx] = f2bf(v);
}

// transposed weights for coalesced GRU / root access
__global__ void k_wT(const float* __restrict__ w_ih, const float* __restrict__ w_hh,
                     const float* __restrict__ Wroot,
                     float* __restrict__ wTih, float* __restrict__ wThh, float* __restrict__ wrT){
    int idx = blockIdx.x*blockDim.x + threadIdx.x;
    if(idx < 3*HD*HD){
        int g = idx / HD, i = idx % HD;
        wTih[i*3*HD + g] = w_ih[idx];
        wThh[i*3*HD + g] = w_hh[idx];
    }
    if(idx < HD*HD){
        int o = idx / HD, i = idx % HD;
        wrT[i*HD + o] = Wroot[idx];
    }
}

// state (n x 64 f32) -> bf16 copy (used once for x)
__global__ void k_cvtA(const float* __restrict__ s, u16* __restrict__ a, int n){
    int i = (blockIdx.x*blockDim.x + threadIdx.x) * 4;
    if(i < n){
        float4 v = *(const float4*)&s[i];
        ushort4 o;
        o.x = f2bf(v.x); o.y = f2bf(v.y); o.z = f2bf(v.z); o.w = f2bf(v.w);
        *(ushort4*)&a[i] = o;
    }
}

// Fused: per block of 16 src nodes: (1) MFMA M-tile = Abf_block @ PT into LDS,
// (2) per-node MFMA msg = h1E_edges @ M^T, scatter-atomic into agg.
// grid = N/16, block = 1024 (16 waves), dyn LDS = LDSB.
// LDS layout: node n at n*NSTR; o-row at o*OSTR (9 slots of 16B; k 0..63 in
// slots (k>>3) swizzled by slot' = (slot + 2o + (o>>3))&7; bias k=64 at byte 128).
__global__ __launch_bounds__(1024) void k_fused(
        const u16* __restrict__ Abf, const u16* __restrict__ PT,
        const u16* __restrict__ h1E, const int* __restrict__ rowptr,
        const int* __restrict__ dstE, int E, float* __restrict__ agg){
    extern __shared__ char smem[];
    int t = threadIdx.x;
    int w = t >> 6;                    // wave 0..15
    int lane = t & 63;
    int r = lane & 15, g = lane >> 4;
    int nb0 = blockIdx.x * NB;

    // ---------------- phase 1: M-tile into LDS ----------------
    // A fragments: rows = 16 nodes of this block (shared across all kc tiles)
    bf16x8 afr0 = *(const bf16x8*)&Abf[(size_t)(nb0 + r)*HD + g*8];
    bf16x8 afr1 = *(const bf16x8*)&Abf[(size_t)(nb0 + r)*HD + 32 + g*8];
    {
        f32x4 acc[4][4];               // [j = kc within group][cb]
        #pragma unroll
        for(int j = 0; j < 4; j++)
            #pragma unroll
            for(int cb = 0; cb < 4; cb++) acc[j][cb] = (f32x4){0.f,0.f,0.f,0.f};
        #pragma unroll
        for(int j = 0; j < 4; j++){
            int kc = 4*w + j;
            const u16* Pb = PT + (size_t)kc*HD*HD;
            #pragma unroll
            for(int cb = 0; cb < 4; cb++){
                bf16x8 b0 = *(const bf16x8*)&Pb[(size_t)(cb*16 + r)*HD + g*8];
                bf16x8 b1 = *(const bf16x8*)&Pb[(size_t)(cb*16 + r)*HD + 32 + g*8];
                acc[j][cb] = __builtin_amdgcn_mfma_f32_16x16x32_bf16(afr0, b0, acc[j][cb], 0,0,0);
                acc[j][cb] = __builtin_amdgcn_mfma_f32_16x16x32_bf16(afr1, b1, acc[j][cb], 0,0,0);
            }
        }
        // write: 4 consecutive k per lane -> one b64 per (cb,reg)
        #pragma unroll
        for(int cb = 0; cb < 4; cb++){
            int o = cb*16 + r;
            int slotp = ((w>>1) + 2*o + (o>>3)) & 7;
            #pragma unroll
            for(int reg = 0; reg < 4; reg++){
                int node = 4*g + reg;
                u32 lo = pk2(acc[0][cb][reg], acc[1][cb][reg]);
                u32 hi = pk2(acc[2][cb][reg], acc[3][cb][reg]);
                *(u64*)(smem + node*NSTR + o*OSTR + slotp*16 + 8*(w&1)) =
                    (u64)lo | ((u64)hi << 32);
            }
        }
        if(w == 0){                    // bias row kc = 64
            f32x4 accB[4];
            #pragma unroll
            for(int cb = 0; cb < 4; cb++) accB[cb] = (f32x4){0.f,0.f,0.f,0.f};
            const u16* Pb = PT + (size_t)64*HD*HD;
            #pragma unroll
            for(int cb = 0; cb < 4; cb++){
                bf16x8 b0 = *(const bf16x8*)&Pb[(size_t)(cb*16 + r)*HD + g*8];
                bf16x8 b1 = *(const bf16x8*)&Pb[(size_t)(cb*16 + r)*HD + 32 + g*8];
                accB[cb] = __builtin_amdgcn_mfma_f32_16x16x32_bf16(afr0, b0, accB[cb], 0,0,0);
                accB[cb] = __builtin_amdgcn_mfma_f32_16x16x32_bf16(afr1, b1, accB[cb], 0,0,0);
            }
            #pragma unroll
            for(int cb = 0; cb < 4; cb++)
                #pragma unroll
                for(int reg = 0; reg < 4; reg++)
                    *(u16*)(smem + (4*g+reg)*NSTR + (cb*16+r)*OSTR + 128) =
                        f2bf(accB[cb][reg]);
        }
    }
    __syncthreads();

    // ---------------- phase 2: scatter via MFMA, wave w -> node w ----------------
    int s = nb0 + w;
    int beg = rowptr[s], end = rowptr[s+1];
    if(beg == end) return;
    const char* nodebase = smem + w*NSTR;
    bf16x8 sB[4][2];
    float bval[4];
    #pragma unroll
    for(int cb = 0; cb < 4; cb++){
        int o = cb*16 + r;
        #pragma unroll
        for(int ks = 0; ks < 2; ks++){
            int slotp = ((ks*4 + g) + 2*o + (o>>3)) & 7;
            sB[cb][ks] = *(const bf16x8*)(nodebase + o*OSTR + slotp*16);
        }
        bval[cb] = bf2f(*(const u16*)(nodebase + o*OSTR + 128));
    }
    for(int p0 = beg; p0 < end; p0 += 16){
        int p = p0 + r;
        int pc = p < E ? p : E-1;
        bf16x8 a0 = *(const bf16x8*)&h1E[(size_t)pc*HD + g*8];
        bf16x8 a1 = *(const bf16x8*)&h1E[(size_t)pc*HD + 32 + g*8];
        f32x4 acc2[4];
        #pragma unroll
        for(int cb = 0; cb < 4; cb++){
            acc2[cb] = (f32x4){0.f,0.f,0.f,0.f};
            acc2[cb] = __builtin_amdgcn_mfma_f32_16x16x32_bf16(a0, sB[cb][0], acc2[cb], 0,0,0);
            acc2[cb] = __builtin_amdgcn_mfma_f32_16x16x32_bf16(a1, sB[cb][1], acc2[cb], 0,0,0);
        }
        int dq[4];
        #pragma unroll
        for(int reg = 0; reg < 4; reg++){
            int q = p0 + 4*g + reg;
            dq[reg] = (q < end) ? dstE[q] : -1;
        }
        #pragma unroll
        for(int cb = 0; cb < 4; cb++)
            #pragma unroll
            for(int reg = 0; reg < 4; reg++)
                if(dq[reg] >= 0)
                    atomicAdd(&agg[(size_t)dq[reg]*HD + cb*16 + r],
                              acc2[cb][reg] + bval[cb]);
    }
}

// merged m + GRU: 16 nodes/block, 256 threads. Writes hnew (f32) and bf16 copy.
__global__ void k_mgru(const float* __restrict__ agg, const float* __restrict__ countsf,
                       const float* __restrict__ state,
                       const float* __restrict__ wrT, const float* __restrict__ bconv,
                       const float* __restrict__ wTih, const float* __restrict__ wThh,
                       const float* __restrict__ b_ih, const float* __restrict__ b_hh,
                       float* __restrict__ hnew, u16* __restrict__ AbfN){
    __shared__ float s_x[NB][HD], s_m[NB][HD], s_gi[NB][192], s_gh[NB][192];
    int n0 = blockIdx.x * NB;
    int t = threadIdx.x;               // 256
    for(int idx = t; idx < NB*HD; idx += 256)
        s_x[idx>>6][idx&63] = state[(size_t)n0*HD + idx];
    __syncthreads();
    for(int idx = t; idx < NB*HD; idx += 256){
        int nl = idx>>6, o = idx&63;
        float rt = bconv[o];
        #pragma unroll 8
        for(int i = 0; i < HD; i++) rt += s_x[nl][i] * wrT[i*HD + o];
        float m = agg[(size_t)(n0+nl)*HD + o] / countsf[n0+nl] + rt;
        s_m[nl][o] = m > 0.f ? m : 0.f;
    }
    __syncthreads();
    for(int idx = t; idx < NB*192; idx += 256){
        int nl = idx/192, g3 = idx%192;
        float gi = b_ih[g3], gh = b_hh[g3];
        #pragma unroll 4
        for(int i = 0; i < HD; i++){
            gi += s_m[nl][i] * wTih[i*192 + g3];
            gh += s_x[nl][i] * wThh[i*192 + g3];
        }
        s_gi[nl][g3] = gi; s_gh[nl][g3] = gh;
    }
    __syncthreads();
    for(int idx = t; idx < NB*HD; idx += 256){
        int nl = idx>>6, o = idx&63;
        float rr = 1.f/(1.f + __expf(-(s_gi[nl][o]      + s_gh[nl][o])));
        float zz = 1.f/(1.f + __expf(-(s_gi[nl][64+o]   + s_gh[nl][64+o])));
        float nnv = tanhf(s_gi[nl][128+o] + rr*s_gh[nl][128+o]);
        float h = (1.f - zz)*nnv + zz*s_x[nl][o];
        hnew[(size_t)(n0+nl)*HD + o] = h;
        AbfN[(size_t)(n0+nl)*HD + o] = f2bf(h);
    }
}

extern "C" void kernel_launch(void* const* d_in, const int* in_sizes, int n_in,
                              void* d_out, int out_size, void* d_ws, size_t ws_size,
                              hipStream_t stream){
    const float* x     = (const float*)d_in[0];
    const float* ea    = (const float*)d_in[1];
    const float* W1    = (const float*)d_in[2];
    const float* b1    = (const float*)d_in[3];
    const float* W2    = (const float*)d_in[4];
    const float* b2    = (const float*)d_in[5];
    const float* Wroot = (const float*)d_in[6];
    const float* bconv = (const float*)d_in[7];
    const float* w_ih  = (const float*)d_in[8];
    const float* w_hh  = (const float*)d_in[9];
    const float* b_ih  = (const float*)d_in[10];
    const float* b_hh  = (const float*)d_in[11];
    const int*   eidx  = (const int*)d_in[12];
    int N = in_sizes[0] / HD;
    int E = in_sizes[1] / ED;
    const int* srcarr = eidx;
    const int* dstarr = eidx + E;

    char* w = (char*)d_ws;
    size_t off = 0;
    auto alloc = [&](size_t bytes)->char*{
        char* p = w + off; off = (off + bytes + 255) & ~(size_t)255; return p;
    };
    int*   deg_src = (int*)alloc((size_t)N*4);
    int*   deg_dst = (int*)alloc((size_t)N*4);
    int*   rowptr  = (int*)alloc((size_t)(N+1)*4);
    int*   cursor  = (int*)alloc((size_t)N*4);
    int*   elist   = (int*)alloc((size_t)E*4);
    int*   dstE    = (int*)alloc((size_t)E*4);
    float* countsf = (float*)alloc((size_t)N*4);
    u16*   h1E     = (u16*)alloc((size_t)E*HD*2);
    u16*   PT      = (u16*)alloc((size_t)65*HD*HD*2);
    u16*   Abf     = (u16*)alloc((size_t)N*HD*2);
    float* wTih    = (float*)alloc((size_t)3*HD*HD*4);
    float* wThh    = (float*)alloc((size_t)3*HD*HD*4);
    float* wrT     = (float*)alloc((size_t)HD*HD*4);
    float* agg     = (float*)alloc((size_t)N*HD*4);
    float* stA     = (float*)alloc((size_t)N*HD*4);
    float* stB     = (float*)alloc((size_t)N*HD*4);

    // allow 147.7 KB dynamic LDS for the fused kernel (idempotent host call)
    hipFuncSetAttribute((const void*)k_fused,
                        hipFuncAttributeMaxDynamicSharedMemorySize, LDSB);

    // ---- precompute ----
    hipLaunchKernelGGL(k_zero2, dim3((N+255)/256), dim3(256), 0, stream, deg_src, deg_dst, N);
    hipLaunchKernelGGL(k_deg,   dim3((E+255)/256), dim3(256), 0, stream, srcarr, dstarr, E, deg_src, deg_dst);
    hipLaunchKernelGGL(k_scan,  dim3(1), dim3(1024), 0, stream, deg_src, deg_dst, N, rowptr, cursor, countsf);
    hipLaunchKernelGGL(k_fill,  dim3((E+255)/256), dim3(256), 0, stream, srcarr, E, cursor, elist);
    hipLaunchKernelGGL(k_h1E,   dim3((E+3)/4), dim3(256), 0, stream, ea, W1, b1, elist, dstarr, E, h1E, dstE);
    hipLaunchKernelGGL(k_permT, dim3((65*HD*HD+255)/256), dim3(256), 0, stream, W2, b2, PT);
    hipLaunchKernelGGL(k_wT,    dim3((3*HD*HD+255)/256), dim3(256), 0, stream, w_ih, w_hh, Wroot, wTih, wThh, wrT);
    hipLaunchKernelGGL(k_cvtA,  dim3((N*HD/4+255)/256), dim3(256), 0, stream, x, Abf, N*HD);

    // ---- 3 message-passing + GRU iterations ----
    const float* state = x;
    for(int it = 0; it < 3; ++it){
        hipLaunchKernelGGL(k_zerof, dim3((N*HD+255)/256), dim3(256), 0, stream, agg, N*HD);
        hipLaunchKernelGGL(k_fused, dim3(N/NB), dim3(1024), LDSB, stream,
                           Abf, PT, h1E, rowptr, dstE, E, agg);
        float* outp = (it == 2) ? (float*)d_out : ((it == 0) ? stA : stB);
        hipLaunchKernelGGL(k_mgru, dim3(N/NB), dim3(256), 0, stream,
                           agg, countsf, state, wrT, bconv, wTih, wThh, b_ih, b_hh,
                           outp, Abf);
        state = outp;
    }
}

// Round 4
// 222.069 us; speedup vs baseline: 1.4983x; 1.4983x over previous
//
#include <hip/hip_runtime.h>

#define HD 64
#define ED 16
#define NB 16                 // nodes per fused block
#define OSTR 144              // bytes per o-row in LDS (9 x 16B slots: k 0..71)
#define NSTR 9232             // bytes per node in LDS (64*144 + 16 pad)
#define LDSB (NB*NSTR)        // 147712 bytes dynamic LDS
#define GSTR 201              // f32 stride for gate staging in k_mgru2

typedef __bf16 bf16x8 __attribute__((ext_vector_type(8)));
typedef float  f32x4  __attribute__((ext_vector_type(4)));
typedef unsigned int u32;
typedef unsigned long long u64;
typedef unsigned short u16;

static inline __device__ float bf2f(u16 u){
    union { u32 i; float f; } v; v.i = ((u32)u) << 16; return v.f;
}
static inline __device__ u16 f2bf(float f){
    union { u32 i; float f; } v; v.f = f;
    u32 r = v.i + 0x7FFF + ((v.i >> 16) & 1);
    return (u16)(r >> 16);
}
static inline __device__ u32 pk2(float a, float b){
    return (u32)f2bf(a) | ((u32)f2bf(b) << 16);
}

__global__ void k_zero2(int* a, int* b, int n){
    int i = blockIdx.x*blockDim.x + threadIdx.x;
    if(i < n){ a[i] = 0; b[i] = 0; }
}
__global__ void k_zerof(float* a, int n){
    int i = blockIdx.x*blockDim.x + threadIdx.x;
    if(i < n) a[i] = 0.f;
}
__global__ void k_deg(const int* __restrict__ src, const int* __restrict__ dst, int E,
                      int* __restrict__ degs, int* __restrict__ degd){
    int e = blockIdx.x*blockDim.x + threadIdx.x;
    if(e < E){ atomicAdd(&degs[src[e]], 1); atomicAdd(&degd[dst[e]], 1); }
}

// single-block scan: deg_src -> rowptr/cursor ; deg_dst -> countsf = max(deg,1)
__global__ void k_scan(const int* __restrict__ degs, const int* __restrict__ degd, int N,
                       int* __restrict__ rowptr, int* __restrict__ cursor, float* __restrict__ countsf){
    __shared__ int part[1024];
    int tid = threadIdx.x;
    int PER = (N + 1023) >> 10;
    int base = tid * PER;
    int local[16];
    int s = 0;
    for(int j = 0; j < PER; j++){
        int idx = base + j;
        int v = (idx < N) ? degs[idx] : 0;
        local[j] = s; s += v;
    }
    part[tid] = s;
    __syncthreads();
    for(int off = 1; off < 1024; off <<= 1){
        int v = (tid >= off) ? part[tid - off] : 0;
        __syncthreads();
        part[tid] += v;
        __syncthreads();
    }
    int prev = (tid == 0) ? 0 : part[tid - 1];
    for(int j = 0; j < PER; j++){
        int idx = base + j;
        if(idx < N){
            int r = prev + local[j];
            rowptr[idx] = r; cursor[idx] = r;
            int dd = degd[idx];
            countsf[idx] = (dd > 0) ? (float)dd : 1.0f;
        }
    }
    if(tid == 1023) rowptr[N] = prev + s;
}

__global__ void k_fill(const int* __restrict__ src, int E, int* __restrict__ cursor, int* __restrict__ elist){
    int e = blockIdx.x*blockDim.x + threadIdx.x;
    if(e < E){ int p = atomicAdd(&cursor[src[e]], 1); elist[p] = e; }
}

// h1E[p] = bf16(relu(edge_attr[elist[p]] @ W1 + b1)) in CSR order; dstE[p] = dst[elist[p]]
__global__ void k_h1E(const float* __restrict__ ea, const float* __restrict__ W1,
                      const float* __restrict__ b1, const int* __restrict__ elist,
                      const int* __restrict__ dstarr, int E,
                      u16* __restrict__ h1E, int* __restrict__ dstE){
    __shared__ float s_ea[4][ED];
    __shared__ int s_e[4];
    int t = threadIdx.x;              // 256
    int o = t & 63, el = t >> 6;
    int p = blockIdx.x*4 + el;
    if(t < 4){
        int pp = blockIdx.x*4 + t;
        s_e[t] = (pp < E) ? elist[pp] : 0;
    }
    __syncthreads();
    if(t < 4*ED){
        int pe = t/ED;
        s_ea[pe][t%ED] = ea[(size_t)s_e[pe]*ED + t%ED];
    }
    __syncthreads();
    if(p < E){
        float acc = b1[o];
        #pragma unroll
        for(int k = 0; k < ED; k++) acc += s_ea[el][k] * W1[k*HD + o];
        h1E[(size_t)p*HD + o] = f2bf(acc > 0.f ? acc : 0.f);
        if(o == 0) dstE[p] = dstarr[s_e[el]];
    }
}

// PT[c][i] = bf16( c=kc*64+o : kc<64 ? W2[kc][i*64+o] : b2[i*64+o] )   (4160 x 64)
__global__ void k_permT(const float* __restrict__ W2, const float* __restrict__ b2,
                        u16* __restrict__ PT){
    int idx = blockIdx.x*blockDim.x + threadIdx.x;
    if(idx >= 65*HD*HD) return;
    int c = idx / HD, i = idx % HD;
    int kc = c >> 6, o = c & 63;
    float v = (kc < HD) ? W2[(size_t)kc*(HD*HD) + i*HD + o] : b2[i*HD + o];
    PT[idx] = f2bf(v);
}

// f32 -> bf16 flat copy (n multiple of 4)
__global__ void k_cvtA(const float* __restrict__ s, u16* __restrict__ a, int n){
    int i = (blockIdx.x*blockDim.x + threadIdx.x) * 4;
    if(i < n){
        float4 v = *(const float4*)&s[i];
        ushort4 o;
        o.x = f2bf(v.x); o.y = f2bf(v.y); o.z = f2bf(v.z); o.w = f2bf(v.w);
        *(ushort4*)&a[i] = o;
    }
}

// Fused: per block of 16 src nodes: (1) MFMA M-tile = Abf_block @ PT into LDS,
// (2) per-node MFMA msg = h1E_edges @ M^T, scatter-atomic into agg.
// grid = N/16, block = 1024 (16 waves), dyn LDS = LDSB.
__global__ __launch_bounds__(1024) void k_fused(
        const u16* __restrict__ Abf, const u16* __restrict__ PT,
        const u16* __restrict__ h1E, const int* __restrict__ rowptr,
        const int* __restrict__ dstE, int E, float* __restrict__ agg){
    extern __shared__ char smem[];
    int t = threadIdx.x;
    int w = t >> 6;                    // wave 0..15
    int lane = t & 63;
    int r = lane & 15, g = lane >> 4;
    int nb0 = blockIdx.x * NB;

    // ---------------- phase 1: M-tile into LDS ----------------
    bf16x8 afr0 = *(const bf16x8*)&Abf[(size_t)(nb0 + r)*HD + g*8];
    bf16x8 afr1 = *(const bf16x8*)&Abf[(size_t)(nb0 + r)*HD + 32 + g*8];
    {
        f32x4 acc[4][4];               // [j = kc within group][cb]
        #pragma unroll
        for(int j = 0; j < 4; j++)
            #pragma unroll
            for(int cb = 0; cb < 4; cb++) acc[j][cb] = (f32x4){0.f,0.f,0.f,0.f};
        #pragma unroll
        for(int j = 0; j < 4; j++){
            int kc = 4*w + j;
            const u16* Pb = PT + (size_t)kc*HD*HD;
            #pragma unroll
            for(int cb = 0; cb < 4; cb++){
                bf16x8 b0 = *(const bf16x8*)&Pb[(size_t)(cb*16 + r)*HD + g*8];
                bf16x8 b1 = *(const bf16x8*)&Pb[(size_t)(cb*16 + r)*HD + 32 + g*8];
                acc[j][cb] = __builtin_amdgcn_mfma_f32_16x16x32_bf16(afr0, b0, acc[j][cb], 0,0,0);
                acc[j][cb] = __builtin_amdgcn_mfma_f32_16x16x32_bf16(afr1, b1, acc[j][cb], 0,0,0);
            }
        }
        #pragma unroll
        for(int cb = 0; cb < 4; cb++){
            int o = cb*16 + r;
            int slotp = ((w>>1) + 2*o + (o>>3)) & 7;
            #pragma unroll
            for(int reg = 0; reg < 4; reg++){
                int node = 4*g + reg;
                u32 lo = pk2(acc[0][cb][reg], acc[1][cb][reg]);
                u32 hi = pk2(acc[2][cb][reg], acc[3][cb][reg]);
                *(u64*)(smem + node*NSTR + o*OSTR + slotp*16 + 8*(w&1)) =
                    (u64)lo | ((u64)hi << 32);
            }
        }
        if(w == 0){                    // bias row kc = 64
            f32x4 accB[4];
            #pragma unroll
            for(int cb = 0; cb < 4; cb++) accB[cb] = (f32x4){0.f,0.f,0.f,0.f};
            const u16* Pb = PT + (size_t)64*HD*HD;
            #pragma unroll
            for(int cb = 0; cb < 4; cb++){
                bf16x8 b0 = *(const bf16x8*)&Pb[(size_t)(cb*16 + r)*HD + g*8];
                bf16x8 b1 = *(const bf16x8*)&Pb[(size_t)(cb*16 + r)*HD + 32 + g*8];
                accB[cb] = __builtin_amdgcn_mfma_f32_16x16x32_bf16(afr0, b0, accB[cb], 0,0,0);
                accB[cb] = __builtin_amdgcn_mfma_f32_16x16x32_bf16(afr1, b1, accB[cb], 0,0,0);
            }
            #pragma unroll
            for(int cb = 0; cb < 4; cb++)
                #pragma unroll
                for(int reg = 0; reg < 4; reg++)
                    *(u16*)(smem + (4*g+reg)*NSTR + (cb*16+r)*OSTR + 128) =
                        f2bf(accB[cb][reg]);
        }
    }
    __syncthreads();

    // ---------------- phase 2: scatter via MFMA, wave w -> node w ----------------
    int s = nb0 + w;
    int beg = rowptr[s], end = rowptr[s+1];
    if(beg == end) return;
    const char* nodebase = smem + w*NSTR;
    bf16x8 sB[4][2];
    float bval[4];
    #pragma unroll
    for(int cb = 0; cb < 4; cb++){
        int o = cb*16 + r;
        #pragma unroll
        for(int ks = 0; ks < 2; ks++){
            int slotp = ((ks*4 + g) + 2*o + (o>>3)) & 7;
            sB[cb][ks] = *(const bf16x8*)(nodebase + o*OSTR + slotp*16);
        }
        bval[cb] = bf2f(*(const u16*)(nodebase + o*OSTR + 128));
    }
    for(int p0 = beg; p0 < end; p0 += 16){
        int p = p0 + r;
        int pc = p < E ? p : E-1;
        bf16x8 a0 = *(const bf16x8*)&h1E[(size_t)pc*HD + g*8];
        bf16x8 a1 = *(const bf16x8*)&h1E[(size_t)pc*HD + 32 + g*8];
        f32x4 acc2[4];
        #pragma unroll
        for(int cb = 0; cb < 4; cb++){
            acc2[cb] = (f32x4){0.f,0.f,0.f,0.f};
            acc2[cb] = __builtin_amdgcn_mfma_f32_16x16x32_bf16(a0, sB[cb][0], acc2[cb], 0,0,0);
            acc2[cb] = __builtin_amdgcn_mfma_f32_16x16x32_bf16(a1, sB[cb][1], acc2[cb], 0,0,0);
        }
        int dq[4];
        #pragma unroll
        for(int reg = 0; reg < 4; reg++){
            int q = p0 + 4*g + reg;
            dq[reg] = (q < end) ? dstE[q] : -1;
        }
        #pragma unroll
        for(int cb = 0; cb < 4; cb++)
            #pragma unroll
            for(int reg = 0; reg < 4; reg++)
                if(dq[reg] >= 0)
                    atomicAdd(&agg[(size_t)dq[reg]*HD + cb*16 + r],
                              acc2[cb][reg] + bval[cb]);
    }
}

// MFMA m+GRU: 16 nodes/block, 256 thr (4 waves). ROOT/GI/GH via mfma_16x16x32_bf16.
// grid = N/16. Reads state f32 + Abf bf16; writes hnew f32 + Abf bf16 (in place, own rows).
__global__ __launch_bounds__(256) void k_mgru2(
        const float* __restrict__ agg, const float* __restrict__ countsf,
        const float* __restrict__ state, const u16* __restrict__ Abf,
        const u16* __restrict__ WrB,  const u16* __restrict__ WihB,
        const u16* __restrict__ WhhB, const float* __restrict__ bconv,
        const float* __restrict__ b_ih, const float* __restrict__ b_hh,
        float* __restrict__ hnew, u16* __restrict__ AbfN){
    __shared__ u16   s_mbf[16*72];            // m bf16, row stride 72 (2-way-free)
    __shared__ float s_gi[16*GSTR];           // gate staging, stride 201
    __shared__ float s_gh[16*GSTR];
    int t = threadIdx.x;
    int w = t >> 6, lane = t & 63;
    int r = lane & 15, g = lane >> 4;
    int n0 = blockIdx.x * 16;

    // state A-fragments (rows = the block's 16 nodes), shared by ROOT and GH
    bf16x8 afr0 = *(const bf16x8*)&Abf[(size_t)(n0 + r)*HD + g*8];
    bf16x8 afr1 = *(const bf16x8*)&Abf[(size_t)(n0 + r)*HD + 32 + g*8];

    // ---- ROOT: cols w*16..w*16+15, bias bconv folded into acc ----
    {
        float bc = bconv[w*16 + r];
        f32x4 accR = (f32x4){bc, bc, bc, bc};
        bf16x8 b0 = *(const bf16x8*)&WrB[(size_t)(w*16 + r)*HD + g*8];
        bf16x8 b1 = *(const bf16x8*)&WrB[(size_t)(w*16 + r)*HD + 32 + g*8];
        accR = __builtin_amdgcn_mfma_f32_16x16x32_bf16(afr0, b0, accR, 0,0,0);
        accR = __builtin_amdgcn_mfma_f32_16x16x32_bf16(afr1, b1, accR, 0,0,0);
        #pragma unroll
        for(int reg = 0; reg < 4; reg++){
            int row = 4*g + reg;
            float cnt = countsf[n0 + row];
            float m = agg[(size_t)(n0 + row)*HD + w*16 + r] / cnt + accR[reg];
            s_mbf[row*72 + w*16 + r] = f2bf(m > 0.f ? m : 0.f);
        }
    }
    __syncthreads();

    // m A-fragments from LDS
    bf16x8 am0 = *(const bf16x8*)&s_mbf[r*72 + g*8];
    bf16x8 am1 = *(const bf16x8*)&s_mbf[r*72 + 32 + g*8];

    // ---- GI = m @ w_ih^T (3 col-tiles per wave), GH = state @ w_hh^T ----
    #pragma unroll
    for(int j = 0; j < 3; j++){
        int cb = w + 4*j;
        int col = cb*16 + r;
        float bi = b_ih[col];
        f32x4 acc = (f32x4){bi, bi, bi, bi};
        bf16x8 b0 = *(const bf16x8*)&WihB[(size_t)col*HD + g*8];
        bf16x8 b1 = *(const bf16x8*)&WihB[(size_t)col*HD + 32 + g*8];
        acc = __builtin_amdgcn_mfma_f32_16x16x32_bf16(am0, b0, acc, 0,0,0);
        acc = __builtin_amdgcn_mfma_f32_16x16x32_bf16(am1, b1, acc, 0,0,0);
        #pragma unroll
        for(int reg = 0; reg < 4; reg++)
            s_gi[(4*g + reg)*GSTR + col] = acc[reg];
    }
    #pragma unroll
    for(int j = 0; j < 3; j++){
        int cb = w + 4*j;
        int col = cb*16 + r;
        float bh = b_hh[col];
        f32x4 acc = (f32x4){bh, bh, bh, bh};
        bf16x8 b0 = *(const bf16x8*)&WhhB[(size_t)col*HD + g*8];
        bf16x8 b1 = *(const bf16x8*)&WhhB[(size_t)col*HD + 32 + g*8];
        acc = __builtin_amdgcn_mfma_f32_16x16x32_bf16(afr0, b0, acc, 0,0,0);
        acc = __builtin_amdgcn_mfma_f32_16x16x32_bf16(afr1, b1, acc, 0,0,0);
        #pragma unroll
        for(int reg = 0; reg < 4; reg++)
            s_gh[(4*g + reg)*GSTR + col] = acc[reg];
    }
    __syncthreads();

    // ---- epilogue: sigmoid/tanh + state update, 4 elements/thread ----
    #pragma unroll
    for(int q = 0; q < 4; q++){
        int idx = t + q*256;              // 0..1023
        int nl = idx >> 6, o = idx & 63;
        const float* gi = s_gi + nl*GSTR;
        const float* gh = s_gh + nl*GSTR;
        float rr  = 1.f/(1.f + __expf(-(gi[o]      + gh[o])));
        float zz  = 1.f/(1.f + __expf(-(gi[64+o]   + gh[64+o])));
        float nnv = tanhf(gi[128+o] + rr*gh[128+o]);
        float xo = state[(size_t)(n0+nl)*HD + o];
        float h = (1.f - zz)*nnv + zz*xo;
        hnew[(size_t)(n0+nl)*HD + o] = h;
        AbfN[(size_t)(n0+nl)*HD + o] = f2bf(h);
    }
}

extern "C" void kernel_launch(void* const* d_in, const int* in_sizes, int n_in,
                              void* d_out, int out_size, void* d_ws, size_t ws_size,
                              hipStream_t stream){
    const float* x     = (const float*)d_in[0];
    const float* ea    = (const float*)d_in[1];
    const float* W1    = (const float*)d_in[2];
    const float* b1    = (const float*)d_in[3];
    const float* W2    = (const float*)d_in[4];
    const float* b2    = (const float*)d_in[5];
    const float* Wroot = (const float*)d_in[6];
    const float* bconv = (const float*)d_in[7];
    const float* w_ih  = (const float*)d_in[8];
    const float* w_hh  = (const float*)d_in[9];
    const float* b_ih  = (const float*)d_in[10];
    const float* b_hh  = (const float*)d_in[11];
    const int*   eidx  = (const int*)d_in[12];
    int N = in_sizes[0] / HD;
    int E = in_sizes[1] / ED;
    const int* srcarr = eidx;
    const int* dstarr = eidx + E;

    char* w = (char*)d_ws;
    size_t off = 0;
    auto alloc = [&](size_t bytes)->char*{
        char* p = w + off; off = (off + bytes + 255) & ~(size_t)255; return p;
    };
    int*   deg_src = (int*)alloc((size_t)N*4);
    int*   deg_dst = (int*)alloc((size_t)N*4);
    int*   rowptr  = (int*)alloc((size_t)(N+1)*4);
    int*   cursor  = (int*)alloc((size_t)N*4);
    int*   elist   = (int*)alloc((size_t)E*4);
    int*   dstE    = (int*)alloc((size_t)E*4);
    float* countsf = (float*)alloc((size_t)N*4);
    u16*   h1E     = (u16*)alloc((size_t)E*HD*2);
    u16*   PT      = (u16*)alloc((size_t)65*HD*HD*2);
    u16*   Abf     = (u16*)alloc((size_t)N*HD*2);
    u16*   WihB    = (u16*)alloc((size_t)3*HD*HD*2);
    u16*   WhhB    = (u16*)alloc((size_t)3*HD*HD*2);
    u16*   WrB     = (u16*)alloc((size_t)HD*HD*2);
    float* agg     = (float*)alloc((size_t)N*HD*4);
    float* stA     = (float*)alloc((size_t)N*HD*4);
    float* stB     = (float*)alloc((size_t)N*HD*4);

    hipFuncSetAttribute((const void*)k_fused,
                        hipFuncAttributeMaxDynamicSharedMemorySize, LDSB);

    // ---- precompute ----
    hipLaunchKernelGGL(k_zero2, dim3((N+255)/256), dim3(256), 0, stream, deg_src, deg_dst, N);
    hipLaunchKernelGGL(k_deg,   dim3((E+255)/256), dim3(256), 0, stream, srcarr, dstarr, E, deg_src, deg_dst);
    hipLaunchKernelGGL(k_scan,  dim3(1), dim3(1024), 0, stream, deg_src, deg_dst, N, rowptr, cursor, countsf);
    hipLaunchKernelGGL(k_fill,  dim3((E+255)/256), dim3(256), 0, stream, srcarr, E, cursor, elist);
    hipLaunchKernelGGL(k_h1E,   dim3((E+3)/4), dim3(256), 0, stream, ea, W1, b1, elist, dstarr, E, h1E, dstE);
    hipLaunchKernelGGL(k_permT, dim3((65*HD*HD+255)/256), dim3(256), 0, stream, W2, b2, PT);
    hipLaunchKernelGGL(k_cvtA,  dim3((3*HD*HD/4+255)/256), dim3(256), 0, stream, w_ih, WihB, 3*HD*HD);
    hipLaunchKernelGGL(k_cvtA,  dim3((3*HD*HD/4+255)/256), dim3(256), 0, stream, w_hh, WhhB, 3*HD*HD);
    hipLaunchKernelGGL(k_cvtA,  dim3((HD*HD/4+255)/256), dim3(256), 0, stream, Wroot, WrB, HD*HD);
    hipLaunchKernelGGL(k_cvtA,  dim3((N*HD/4+255)/256), dim3(256), 0, stream, x, Abf, N*HD);

    // ---- 3 message-passing + GRU iterations ----
    const float* state = x;
    for(int it = 0; it < 3; ++it){
        hipLaunchKernelGGL(k_zerof, dim3((N*HD+255)/256), dim3(256), 0, stream, agg, N*HD);
        hipLaunchKernelGGL(k_fused, dim3(N/NB), dim3(1024), LDSB, stream,
                           Abf, PT, h1E, rowptr, dstE, E, agg);
        float* outp = (it == 2) ? (float*)d_out : ((it == 0) ? stA : stB);
        hipLaunchKernelGGL(k_mgru2, dim3(N/16), dim3(256), 0, stream,
                           agg, countsf, state, Abf, WrB, WihB, WhhB,
                           bconv, b_ih, b_hh, outp, Abf);
        state = outp;
    }
}